// Round 1
// baseline (372.234 us; speedup 1.0000x reference)
//
#include <hip/hip_runtime.h>

#define SQ 2048
#define DM 1024
#define NH 16
#define HD 64
#define MTOT 4096  // B*SQ

typedef __bf16 bf16x8 __attribute__((ext_vector_type(8)));
typedef float f32x4 __attribute__((ext_vector_type(4)));
typedef unsigned short u16;
typedef u16 u16x4 __attribute__((ext_vector_type(4)));

// fp32 -> bf16 round-to-nearest-even
__device__ __forceinline__ u16 f2b(float f) {
  union { float f; unsigned u; } c; c.f = f;
  return (u16)((c.u + 0x7FFFu + ((c.u >> 16) & 1u)) >> 16);
}

// ---------------------------------------------------------------------------
// Shared 128x128x1024 NT GEMM core: C = A * W^T, A:[M][1024] f32, W:[N][1024] f32.
// Staging converts f32->bf16 into LDS ([128][48] padded, 16B-aligned rows).
// 4 waves, each computes a 64x64 quadrant via 4x4 frags of 16x16x32 MFMA.
// ---------------------------------------------------------------------------
__device__ __forceinline__ void gemm_core(const float* __restrict__ Ag,
                                          const float* __restrict__ Bg,
                                          u16* sA, u16* sB,
                                          int m0, int n0, f32x4 acc[4][4]) {
  const int t = threadIdx.x;
  const int l = t & 63, w = t >> 6;
  const int wr = w >> 1, wc = w & 1, lg = l >> 4, li = l & 15;
  const int srow = t >> 1, skh = (t & 1) << 4;

  const float* ga = Ag + (size_t)(m0 + srow) * DM + skh;
  const float* gb = Bg + (size_t)(n0 + srow) * DM + skh;
  u16* wa = sA + srow * 48 + skh;
  u16* wb = sB + srow * 48 + skh;

  for (int kt = 0; kt < DM / 32; ++kt) {
#pragma unroll
    for (int i = 0; i < 4; ++i) {
      float4 a = *(const float4*)(ga + kt * 32 + 4 * i);
      float4 b = *(const float4*)(gb + kt * 32 + 4 * i);
      u16x4 pa = {f2b(a.x), f2b(a.y), f2b(a.z), f2b(a.w)};
      u16x4 pb = {f2b(b.x), f2b(b.y), f2b(b.z), f2b(b.w)};
      *(u16x4*)(wa + 4 * i) = pa;
      *(u16x4*)(wb + 4 * i) = pb;
    }
    __syncthreads();
    bf16x8 aF[4], bF[4];
#pragma unroll
    for (int mi = 0; mi < 4; ++mi)
      aF[mi] = *(const bf16x8*)(sA + (wr * 64 + mi * 16 + li) * 48 + lg * 8);
#pragma unroll
    for (int ni = 0; ni < 4; ++ni)
      bF[ni] = *(const bf16x8*)(sB + (wc * 64 + ni * 16 + li) * 48 + lg * 8);
#pragma unroll
    for (int mi = 0; mi < 4; ++mi)
#pragma unroll
      for (int ni = 0; ni < 4; ++ni)
        acc[mi][ni] = __builtin_amdgcn_mfma_f32_16x16x32_bf16(aF[mi], bF[ni], acc[mi][ni], 0, 0, 0);
    __syncthreads();
  }
}

// ---------------------------------------------------------------------------
// QKV projection: z = 0:Q (scaled 1/8), 1:K, 2:V (stored transposed [bh][dd][s])
// ---------------------------------------------------------------------------
__global__ void __launch_bounds__(256) qkv_gemm(
    const float* __restrict__ X,
    const float* __restrict__ Wq, const float* __restrict__ Wk, const float* __restrict__ Wv,
    const float* __restrict__ bq, const float* __restrict__ bk, const float* __restrict__ bv,
    u16* __restrict__ Qb, u16* __restrict__ Kb, u16* __restrict__ Vt) {
  __shared__ u16 sA[128 * 48];
  __shared__ u16 sB[128 * 48];
  const int mode = blockIdx.z;
  const float* W = (mode == 0) ? Wq : (mode == 1) ? Wk : Wv;
  const float* bias = (mode == 0) ? bq : (mode == 1) ? bk : bv;
  const int m0 = blockIdx.y * 128, n0 = blockIdx.x * 128;

  f32x4 acc[4][4];
  f32x4 z4 = {0.f, 0.f, 0.f, 0.f};
#pragma unroll
  for (int i = 0; i < 4; ++i)
#pragma unroll
    for (int j = 0; j < 4; ++j) acc[i][j] = z4;

  gemm_core(X, W, sA, sB, m0, n0, acc);

  const int t = threadIdx.x;
  const int l = t & 63, w = t >> 6;
  const int wr = w >> 1, wc = w & 1, lg = l >> 4, li = l & 15;
#pragma unroll
  for (int mi = 0; mi < 4; ++mi) {
    const int m = m0 + wr * 64 + mi * 16 + lg * 4;
    const int b = m >> 11;           // batch
    const int s = m & 2047;          // seq pos
#pragma unroll
    for (int ni = 0; ni < 4; ++ni) {
      const int n = n0 + wc * 64 + ni * 16 + li;
      const int h = n >> 6, dd = n & 63;
      const float bia = bias[n];
      const size_t bh = (size_t)(b * NH + h);
#pragma unroll
      for (int r = 0; r < 4; ++r) {
        const float val = acc[mi][ni][r] + bia;
        const int ss = s + r;
        if (mode == 0)      Qb[(bh * SQ + ss) * HD + dd] = f2b(val * 0.125f);
        else if (mode == 1) Kb[(bh * SQ + ss) * HD + dd] = f2b(val);
        else                Vt[(bh * HD + dd) * SQ + ss] = f2b(val);
      }
    }
  }
}

// ---------------------------------------------------------------------------
// Final projection: out = A * Wo^T + bo (fp32 out)
// ---------------------------------------------------------------------------
__global__ void __launch_bounds__(256) out_gemm(
    const float* __restrict__ Ag, const float* __restrict__ Wo,
    const float* __restrict__ bo, float* __restrict__ out) {
  __shared__ u16 sA[128 * 48];
  __shared__ u16 sB[128 * 48];
  const int m0 = blockIdx.y * 128, n0 = blockIdx.x * 128;

  f32x4 acc[4][4];
  f32x4 z4 = {0.f, 0.f, 0.f, 0.f};
#pragma unroll
  for (int i = 0; i < 4; ++i)
#pragma unroll
    for (int j = 0; j < 4; ++j) acc[i][j] = z4;

  gemm_core(Ag, Wo, sA, sB, m0, n0, acc);

  const int t = threadIdx.x;
  const int l = t & 63, w = t >> 6;
  const int wr = w >> 1, wc = w & 1, lg = l >> 4, li = l & 15;
#pragma unroll
  for (int mi = 0; mi < 4; ++mi) {
    const int m = m0 + wr * 64 + mi * 16 + lg * 4;
#pragma unroll
    for (int ni = 0; ni < 4; ++ni) {
      const int n = n0 + wc * 64 + ni * 16 + li;
      const float bia = bo[n];
#pragma unroll
      for (int r = 0; r < 4; ++r)
        out[(size_t)(m + r) * DM + n] = acc[mi][ni][r] + bia;
    }
  }
}

// ---------------------------------------------------------------------------
// Flash attention, faithful to reference masking: query rows >= valid_len get
// all scores = -1e6 (-> uniform softmax -> mean(V)), no key masking.
// Q pre-scaled by 1/8. 4 waves x 16 q-rows, 64-key tiles, online softmax.
// ---------------------------------------------------------------------------
__global__ void __launch_bounds__(256) attn_kernel(
    const u16* __restrict__ Qb, const u16* __restrict__ Kb, const u16* __restrict__ Vt,
    const int* __restrict__ vlen, float* __restrict__ Ao) {
  __shared__ u16 sP[4][16][72];  // per-wave P strip, padded (144B rows: 16B-aligned, 2-way max)
  const int bh = blockIdx.y;
  const int qt = blockIdx.x;
  const int t = threadIdx.x;
  const int w = t >> 6, l = t & 63, lg = l >> 4, li = l & 15;
  const int vl = vlen[bh];
  const u16* Qh = Qb + (size_t)bh * SQ * HD;
  const u16* Kh = Kb + (size_t)bh * SQ * HD;
  const u16* Vh = Vt + (size_t)bh * HD * SQ;
  const int q0 = qt * 64 + w * 16;

  bf16x8 qf[2];
#pragma unroll
  for (int kk = 0; kk < 2; ++kk)
    qf[kk] = *(const bf16x8*)(Qh + (size_t)(q0 + li) * HD + kk * 32 + lg * 8);

  float m_r[4] = {-1e30f, -1e30f, -1e30f, -1e30f};
  float l_r[4] = {0.f, 0.f, 0.f, 0.f};
  f32x4 z4 = {0.f, 0.f, 0.f, 0.f};
  f32x4 o[4];
#pragma unroll
  for (int ni = 0; ni < 4; ++ni) o[ni] = z4;

  bool mk[4];
#pragma unroll
  for (int r = 0; r < 4; ++r) mk[r] = (q0 + lg * 4 + r) >= vl;

  for (int kt = 0; kt < SQ / 64; ++kt) {
    // S = Q K^T (Q already scaled by 1/8)
    f32x4 sc[4];
#pragma unroll
    for (int ni = 0; ni < 4; ++ni) {
      f32x4 sa = z4;
#pragma unroll
      for (int kk = 0; kk < 2; ++kk) {
        bf16x8 kf = *(const bf16x8*)(Kh + (size_t)(kt * 64 + ni * 16 + li) * HD + kk * 32 + lg * 8);
        sa = __builtin_amdgcn_mfma_f32_16x16x32_bf16(qf[kk], kf, sa, 0, 0, 0);
      }
      sc[ni] = sa;
    }
    // online softmax per row (row = lg*4+r, 16 lanes of li hold its 64 cols)
    float alpha[4];
#pragma unroll
    for (int r = 0; r < 4; ++r) {
      float s0 = mk[r] ? -1e6f : sc[0][r];
      float s1 = mk[r] ? -1e6f : sc[1][r];
      float s2 = mk[r] ? -1e6f : sc[2][r];
      float s3 = mk[r] ? -1e6f : sc[3][r];
      float pm = fmaxf(fmaxf(s0, s1), fmaxf(s2, s3));
      pm = fmaxf(pm, __shfl_xor(pm, 1));
      pm = fmaxf(pm, __shfl_xor(pm, 2));
      pm = fmaxf(pm, __shfl_xor(pm, 4));
      pm = fmaxf(pm, __shfl_xor(pm, 8));
      const float mn = fmaxf(m_r[r], pm);
      const float al = __expf(m_r[r] - mn);
      const float p0 = __expf(s0 - mn), p1 = __expf(s1 - mn);
      const float p2 = __expf(s2 - mn), p3 = __expf(s3 - mn);
      float ps = p0 + p1 + p2 + p3;
      ps += __shfl_xor(ps, 1);
      ps += __shfl_xor(ps, 2);
      ps += __shfl_xor(ps, 4);
      ps += __shfl_xor(ps, 8);
      l_r[r] = l_r[r] * al + ps;
      m_r[r] = mn;
      alpha[r] = al;
      sP[w][lg * 4 + r][li]      = f2b(p0);
      sP[w][lg * 4 + r][16 + li] = f2b(p1);
      sP[w][lg * 4 + r][32 + li] = f2b(p2);
      sP[w][lg * 4 + r][48 + li] = f2b(p3);
    }
#pragma unroll
    for (int ni = 0; ni < 4; ++ni) {
      o[ni][0] *= alpha[0]; o[ni][1] *= alpha[1];
      o[ni][2] *= alpha[2]; o[ni][3] *= alpha[3];
    }
    // P (D-layout) -> A-layout via same-wave LDS round-trip (in-order DS pipe)
    bf16x8 pf[2];
#pragma unroll
    for (int kk = 0; kk < 2; ++kk)
      pf[kk] = *(const bf16x8*)(&sP[w][li][kk * 32 + lg * 8]);
#pragma unroll
    for (int ni = 0; ni < 4; ++ni) {
#pragma unroll
      for (int kk = 0; kk < 2; ++kk) {
        bf16x8 vf = *(const bf16x8*)(Vh + (size_t)(ni * 16 + li) * SQ + kt * 64 + kk * 32 + lg * 8);
        o[ni] = __builtin_amdgcn_mfma_f32_16x16x32_bf16(pf[kk], vf, o[ni], 0, 0, 0);
      }
    }
  }

  const int b = bh >> 4, h = bh & 15;
  float inv[4];
#pragma unroll
  for (int r = 0; r < 4; ++r) inv[r] = 1.0f / l_r[r];
#pragma unroll
  for (int ni = 0; ni < 4; ++ni) {
#pragma unroll
    for (int r = 0; r < 4; ++r) {
      const int s = q0 + lg * 4 + r;
      Ao[((size_t)b * SQ + s) * DM + h * HD + ni * 16 + li] = o[ni][r] * inv[r];
    }
  }
}

extern "C" void kernel_launch(void* const* d_in, const int* in_sizes, int n_in,
                              void* d_out, int out_size, void* d_ws, size_t ws_size,
                              hipStream_t stream) {
  const float* X  = (const float*)d_in[0];
  const float* Wq = (const float*)d_in[1];
  const float* bq = (const float*)d_in[2];
  const float* Wk = (const float*)d_in[3];
  const float* bk = (const float*)d_in[4];
  const float* Wv = (const float*)d_in[5];
  const float* bv = (const float*)d_in[6];
  const float* Wo = (const float*)d_in[7];
  const float* bo = (const float*)d_in[8];
  const int* vlen = (const int*)d_in[9];

  char* ws = (char*)d_ws;
  u16* Qb   = (u16*)(ws);                          // 8 MB: [32][2048][64] bf16
  u16* Kb   = (u16*)(ws + (size_t)8388608);        // 8 MB: [32][2048][64] bf16
  u16* Vt   = (u16*)(ws + (size_t)16777216);       // 8 MB: [32][64][2048] bf16 (transposed)
  float* Ao = (float*)(ws + (size_t)25165824);     // 16 MB: [2][2048][1024] f32

  dim3 blk(256);
  qkv_gemm<<<dim3(8, 32, 3), blk, 0, stream>>>(X, Wq, Wk, Wv, bq, bk, bv, Qb, Kb, Vt);
  attn_kernel<<<dim3(32, 32), blk, 0, stream>>>(Qb, Kb, Vt, vlen, Ao);
  out_gemm<<<dim3(8, 32), blk, 0, stream>>>(Ao, Wo, bo, (float*)d_out);
}

// Round 2
// 168.530 us; speedup vs baseline: 2.2087x; 2.2087x over previous
//
#include <hip/hip_runtime.h>

#define SQ 2048
#define DM 1024
#define NH 16
#define HD 64

typedef __bf16 bf16x8 __attribute__((ext_vector_type(8)));
typedef float f32x4 __attribute__((ext_vector_type(4)));
typedef unsigned short u16;
typedef unsigned int u32;

// fp32 -> bf16 round-to-nearest-even
__device__ __forceinline__ u16 f2b(float f) {
  union { float f; u32 u; } c; c.f = f;
  return (u16)((c.u + 0x7FFFu + ((c.u >> 16) & 1u)) >> 16);
}

// async global->LDS, 16B per lane; lds dest = wave-uniform base + lane*16
__device__ __forceinline__ void gll16(const void* g, void* l) {
  __builtin_amdgcn_global_load_lds(
      (const __attribute__((address_space(1))) void*)g,
      (__attribute__((address_space(3))) void*)l, 16, 0, 0);
}

// ---------------------------------------------------------------------------
// fp32 -> bf16 convert pass: X (4M elems) + Wq/Wk/Wv/Wo (1M each)
// ---------------------------------------------------------------------------
__global__ void __launch_bounds__(256) conv_bf16(
    const float* __restrict__ X,
    const float* __restrict__ Wq, const float* __restrict__ Wk,
    const float* __restrict__ Wv, const float* __restrict__ Wo,
    u16* __restrict__ Xb, u16* __restrict__ Wqb, u16* __restrict__ Wkb,
    u16* __restrict__ Wvb, u16* __restrict__ Wob) {
  const size_t e = ((size_t)blockIdx.x * 256 + threadIdx.x) * 8;
  const float* src; u16* dst; size_t rel;
  if (e < 4194304u)      { src = X;  dst = Xb;  rel = e; }
  else if (e < 5242880u) { src = Wq; dst = Wqb; rel = e - 4194304u; }
  else if (e < 6291456u) { src = Wk; dst = Wkb; rel = e - 5242880u; }
  else if (e < 7340032u) { src = Wv; dst = Wvb; rel = e - 6291456u; }
  else                   { src = Wo; dst = Wob; rel = e - 7340032u; }
  float4 a = *(const float4*)(src + rel);
  float4 b = *(const float4*)(src + rel + 4);
  union { u16 h[8]; uint4 v; } o;
  o.h[0] = f2b(a.x); o.h[1] = f2b(a.y); o.h[2] = f2b(a.z); o.h[3] = f2b(a.w);
  o.h[4] = f2b(b.x); o.h[5] = f2b(b.y); o.h[6] = f2b(b.z); o.h[7] = f2b(b.w);
  *(uint4*)(dst + rel) = o.v;
}

// ---------------------------------------------------------------------------
// m97-style 128x128 NT GEMM core, bf16 inputs, BK=32, global_load_lds staging,
// double-buffered LDS ([2][128][32] linear per operand), 2-phase schedule.
// ---------------------------------------------------------------------------
__device__ __forceinline__ void stage128(const u16* __restrict__ A, const u16* __restrict__ B,
                                         u16* sA, u16* sB, int m0, int n0, int kt,
                                         int w, int l) {
#pragma unroll
  for (int c = 0; c < 2; ++c) {
    const int g = w * 2 + c;       // chunk-group 0..7 (1 KB each)
    const int s = g * 64 + l;      // 16B slot 0..511
    const int r = s >> 2, cc = s & 3;
    gll16(A + (size_t)(m0 + r) * DM + kt * 32 + cc * 8, sA + g * 512);
    gll16(B + (size_t)(n0 + r) * DM + kt * 32 + cc * 8, sB + g * 512);
  }
}

__device__ __forceinline__ void gemm_core2(const u16* __restrict__ A, const u16* __restrict__ B,
                                           u16* sA, u16* sB,   // each [2][4096] u16
                                           int m0, int n0, f32x4 acc[4][4]) {
  const int t = threadIdx.x, l = t & 63, w = t >> 6;
  const int wr = w >> 1, wc = w & 1, lg = l >> 4, li = l & 15;

  stage128(A, B, sA, sB, m0, n0, 0, w, l);
  __syncthreads();  // drains vmcnt(0) before barrier
  int cur = 0;
  for (int kt = 0; kt < DM / 32; ++kt) {
    if (kt + 1 < DM / 32)
      stage128(A, B, sA + (cur ^ 1) * 4096, sB + (cur ^ 1) * 4096, m0, n0, kt + 1, w, l);
    bf16x8 aF[4], bF[4];
#pragma unroll
    for (int mi = 0; mi < 4; ++mi)
      aF[mi] = *(const bf16x8*)(sA + cur * 4096 + (wr * 64 + mi * 16 + li) * 32 + lg * 8);
#pragma unroll
    for (int ni = 0; ni < 4; ++ni)
      bF[ni] = *(const bf16x8*)(sB + cur * 4096 + (wc * 64 + ni * 16 + li) * 32 + lg * 8);
#pragma unroll
    for (int mi = 0; mi < 4; ++mi)
#pragma unroll
      for (int ni = 0; ni < 4; ++ni)
        acc[mi][ni] = __builtin_amdgcn_mfma_f32_16x16x32_bf16(aF[mi], bF[ni], acc[mi][ni], 0, 0, 0);
    __syncthreads();
    cur ^= 1;
  }
}

// ---------------------------------------------------------------------------
// QKV projection (bf16 in): z = 0:Q (scaled 1/8), 1:K, 2:V^T ([bh][dd][s])
// ---------------------------------------------------------------------------
__global__ void __launch_bounds__(256) qkv_gemm(
    const u16* __restrict__ Xb,
    const u16* __restrict__ Wqb, const u16* __restrict__ Wkb, const u16* __restrict__ Wvb,
    const float* __restrict__ bq, const float* __restrict__ bk, const float* __restrict__ bv,
    u16* __restrict__ Qb, u16* __restrict__ Kb, u16* __restrict__ Vt) {
  __shared__ u16 sA[8192];
  __shared__ u16 sB[8192];
  const int mode = blockIdx.z;
  const u16* W = (mode == 0) ? Wqb : (mode == 1) ? Wkb : Wvb;
  const float* bias = (mode == 0) ? bq : (mode == 1) ? bk : bv;
  const int m0 = blockIdx.y * 128, n0 = blockIdx.x * 128;

  f32x4 acc[4][4];
  f32x4 z4 = {0.f, 0.f, 0.f, 0.f};
#pragma unroll
  for (int i = 0; i < 4; ++i)
#pragma unroll
    for (int j = 0; j < 4; ++j) acc[i][j] = z4;

  gemm_core2(Xb, W, sA, sB, m0, n0, acc);

  const int t = threadIdx.x;
  const int l = t & 63, w = t >> 6;
  const int wr = w >> 1, wc = w & 1, lg = l >> 4, li = l & 15;
#pragma unroll
  for (int mi = 0; mi < 4; ++mi) {
    const int m = m0 + wr * 64 + mi * 16 + lg * 4;
    const int b = m >> 11;           // batch
    const int s = m & 2047;          // seq pos
#pragma unroll
    for (int ni = 0; ni < 4; ++ni) {
      const int n = n0 + wc * 64 + ni * 16 + li;
      const int h = n >> 6, dd = n & 63;
      const float bia = bias[n];
      const size_t bh = (size_t)(b * NH + h);
#pragma unroll
      for (int r = 0; r < 4; ++r) {
        const float val = acc[mi][ni][r] + bia;
        const int ss = s + r;
        if (mode == 0)      Qb[(bh * SQ + ss) * HD + dd] = f2b(val * 0.125f);
        else if (mode == 1) Kb[(bh * SQ + ss) * HD + dd] = f2b(val);
        else                Vt[(bh * HD + dd) * SQ + ss] = f2b(val);
      }
    }
  }
}

// ---------------------------------------------------------------------------
// Final projection: out = Ao * Wo^T + bo (bf16 in, fp32 out)
// ---------------------------------------------------------------------------
__global__ void __launch_bounds__(256) out_gemm(
    const u16* __restrict__ Ag, const u16* __restrict__ Wob,
    const float* __restrict__ bo, float* __restrict__ out) {
  __shared__ u16 sA[8192];
  __shared__ u16 sB[8192];
  const int m0 = blockIdx.y * 128, n0 = blockIdx.x * 128;

  f32x4 acc[4][4];
  f32x4 z4 = {0.f, 0.f, 0.f, 0.f};
#pragma unroll
  for (int i = 0; i < 4; ++i)
#pragma unroll
    for (int j = 0; j < 4; ++j) acc[i][j] = z4;

  gemm_core2(Ag, Wob, sA, sB, m0, n0, acc);

  const int t = threadIdx.x;
  const int l = t & 63, w = t >> 6;
  const int wr = w >> 1, wc = w & 1, lg = l >> 4, li = l & 15;
#pragma unroll
  for (int mi = 0; mi < 4; ++mi) {
    const int m = m0 + wr * 64 + mi * 16 + lg * 4;
#pragma unroll
    for (int ni = 0; ni < 4; ++ni) {
      const int n = n0 + wc * 64 + ni * 16 + li;
      const float bia = bo[n];
#pragma unroll
      for (int r = 0; r < 4; ++r)
        out[(size_t)(m + r) * DM + n] = acc[mi][ni][r] + bia;
    }
  }
}

// ---------------------------------------------------------------------------
// Flash attention v2: swapped QK^T (mfma(K,Q)) -> query-per-lane softmax,
// K/V tiles staged in LDS via global_load_lds (dbuf, chunk-XOR swizzle),
// P -> PV B-operand via 16-shfl in-register exchange. Writes Ao in bf16.
// Faithful masking: query rows >= valid_len get all scores = -1e6.
// ---------------------------------------------------------------------------
__global__ void __launch_bounds__(256) attn_v2(
    const u16* __restrict__ Qb, const u16* __restrict__ Kb, const u16* __restrict__ Vt,
    const int* __restrict__ vlen, u16* __restrict__ Ao) {
  __shared__ u16 sK[2][4096];   // [64 keys][64 dk] bf16, chunk-swizzled
  __shared__ u16 sV[2][4096];   // [64 d][64 keys] bf16 (V^T), chunk-swizzled
  const int bh = blockIdx.y, qt = blockIdx.x;
  const int t = threadIdx.x, w = t >> 6, l = t & 63, lg = l >> 4, li = l & 15;
  const int vl = vlen[bh];
  const u16* Qh = Qb + (size_t)bh * SQ * HD;
  const u16* Kh = Kb + (size_t)bh * SQ * HD;
  const u16* Vh = Vt + (size_t)bh * HD * SQ;
  const int q0 = qt * 64 + w * 16;        // this wave's 16 queries
  const bool mq = (q0 + li) >= vl;        // per-lane row mask

  // Q fragment (B operand): lane holds Q[q0+li][kk*32 + lg*8 .. +7]
  bf16x8 qf[2];
#pragma unroll
  for (int kk = 0; kk < 2; ++kk)
    qf[kk] = *(const bf16x8*)(Qh + (size_t)(q0 + li) * HD + kk * 32 + lg * 8);

  float m_r = -1e30f, l_r = 0.f;
  f32x4 z4 = {0.f, 0.f, 0.f, 0.f};
  f32x4 acc[4];                           // O^T: acc[ni][r] = O^T[ni*16+lg*4+r][q0+li]
#pragma unroll
  for (int ni = 0; ni < 4; ++ni) acc[ni] = z4;

  // stage K/V tile kt into buf (rule 21: linear LDS dest, inverse-swizzled source)
  auto stageKV = [&](int buf, int kt) {
#pragma unroll
    for (int c = 0; c < 2; ++c) {
      const int g = w * 2 + c;        // 0..7
      const int s = g * 64 + l;       // 16B slot 0..511
      const int r = s >> 3, cs = s & 7;
      const int csrc = cs ^ (r & 7);
      gll16(Kh + (size_t)(kt * 64 + r) * HD + csrc * 8, &sK[buf][g * 512]);
      gll16(Vh + (size_t)r * SQ + (size_t)(kt * 64) + csrc * 8, &sV[buf][g * 512]);
    }
  };

  stageKV(0, 0);
  __syncthreads();
  int cur = 0;
  for (int kt = 0; kt < SQ / 64; ++kt) {
    if (kt + 1 < SQ / 64) stageKV(cur ^ 1, kt + 1);

    // S^T = K Q^T : sc[ni][r] = S[key = kt*64+ni*16+lg*4+r][q = q0+li]
    f32x4 sc[4];
#pragma unroll
    for (int ni = 0; ni < 4; ++ni) {
      f32x4 s = z4;
#pragma unroll
      for (int kk = 0; kk < 2; ++kk) {
        const int row = ni * 16 + li;
        bf16x8 kf = *(const bf16x8*)(&sK[cur][row * 64 + (((kk * 4 + lg) ^ (row & 7)) * 8)]);
        s = __builtin_amdgcn_mfma_f32_16x16x32_bf16(kf, qf[kk], s, 0, 0, 0);
      }
      sc[ni] = s;
    }

    // mask + online softmax (query-per-lane; reduce over lg via 2 shfls)
    float pm = -1e30f;
#pragma unroll
    for (int ni = 0; ni < 4; ++ni)
#pragma unroll
      for (int r = 0; r < 4; ++r) {
        const float v = mq ? -1e6f : sc[ni][r];
        sc[ni][r] = v;
        pm = fmaxf(pm, v);
      }
    pm = fmaxf(pm, __shfl_xor(pm, 16));
    pm = fmaxf(pm, __shfl_xor(pm, 32));
    const float mn = fmaxf(m_r, pm);
    const float al = __expf(m_r - mn);
    float p[4][4];
    float ls = 0.f;
#pragma unroll
    for (int ni = 0; ni < 4; ++ni)
#pragma unroll
      for (int r = 0; r < 4; ++r) {
        p[ni][r] = __expf(sc[ni][r] - mn);
        ls += p[ni][r];
      }
    ls += __shfl_xor(ls, 16);
    ls += __shfl_xor(ls, 32);
    l_r = l_r * al + ls;
    m_r = mn;
#pragma unroll
    for (int ni = 0; ni < 4; ++ni) acc[ni] *= al;

    // pack P to bf16 pairs: pk[ni][h] = keys ni*16+lg*4+{2h,2h+1} (query li)
    u32 pk[4][2];
#pragma unroll
    for (int ni = 0; ni < 4; ++ni)
#pragma unroll
      for (int h = 0; h < 2; ++h)
        pk[ni][h] = (u32)f2b(p[ni][2 * h]) | ((u32)f2b(p[ni][2 * h + 1]) << 16);

    // exchange: dest lane (lg,li) builds B-frag rows kk*32+lg*8+j, col=li
    const int srcA = ((lg & 1) << 5) + li;   // lane of lg_s = 2*(lg&1)
    const int srcB = srcA + 16;              // lane of lg_s+1
    u32 rA[4][2], rB[4][2];
#pragma unroll
    for (int ni = 0; ni < 4; ++ni)
#pragma unroll
      for (int h = 0; h < 2; ++h) {
        rA[ni][h] = (u32)__shfl((int)pk[ni][h], srcA);
        rB[ni][h] = (u32)__shfl((int)pk[ni][h], srcB);
      }
    const bool hiSel = ((lg >> 1) & 1) != 0;
    bf16x8 pb[2];
#pragma unroll
    for (int kk = 0; kk < 2; ++kk) {
      union { u32 u[4]; bf16x8 v; } cv;
      cv.u[0] = hiSel ? rA[kk * 2 + 1][0] : rA[kk * 2][0];
      cv.u[1] = hiSel ? rA[kk * 2 + 1][1] : rA[kk * 2][1];
      cv.u[2] = hiSel ? rB[kk * 2 + 1][0] : rB[kk * 2][0];
      cv.u[3] = hiSel ? rB[kk * 2 + 1][1] : rB[kk * 2][1];
      pb[kk] = cv.v;
    }

    // O^T += V^T P^T
#pragma unroll
    for (int ni = 0; ni < 4; ++ni)
#pragma unroll
      for (int kk = 0; kk < 2; ++kk) {
        const int row = ni * 16 + li;
        bf16x8 vf = *(const bf16x8*)(&sV[cur][row * 64 + (((kk * 4 + lg) ^ (row & 7)) * 8)]);
        acc[ni] = __builtin_amdgcn_mfma_f32_16x16x32_bf16(vf, pb[kk], acc[ni], 0, 0, 0);
      }

    __syncthreads();
    cur ^= 1;
  }

  // epilogue: normalize, write bf16 Ao[b][s][h*64+d] (paired u32 stores)
  const int b = bh >> 4, h = bh & 15;
  const float inv = 1.0f / l_r;
#pragma unroll
  for (int ni = 0; ni < 4; ++ni)
#pragma unroll
    for (int hh = 0; hh < 2; ++hh) {
      const u32 v = (u32)f2b(acc[ni][2 * hh] * inv) |
                    ((u32)f2b(acc[ni][2 * hh + 1] * inv) << 16);
      const size_t off = ((size_t)(b * SQ + q0 + li)) * DM + h * HD + ni * 16 + lg * 4 + 2 * hh;
      *(u32*)(Ao + off) = v;
    }
}

extern "C" void kernel_launch(void* const* d_in, const int* in_sizes, int n_in,
                              void* d_out, int out_size, void* d_ws, size_t ws_size,
                              hipStream_t stream) {
  const float* X  = (const float*)d_in[0];
  const float* Wq = (const float*)d_in[1];
  const float* bq = (const float*)d_in[2];
  const float* Wk = (const float*)d_in[3];
  const float* bk = (const float*)d_in[4];
  const float* Wv = (const float*)d_in[5];
  const float* bv = (const float*)d_in[6];
  const float* Wo = (const float*)d_in[7];
  const float* bo = (const float*)d_in[8];
  const int* vlen = (const int*)d_in[9];

  char* ws = (char*)d_ws;
  u16* Qb  = (u16*)(ws);                       // 8 MB [32][2048][64]
  u16* Kb  = (u16*)(ws + (size_t)8388608);     // 8 MB
  u16* Vt  = (u16*)(ws + (size_t)16777216);    // 8 MB [32][64][2048]
  u16* Xb  = (u16*)(ws + (size_t)25165824);    // 8 MB [4096][1024] bf16
  u16* Ao  = Xb;                               // alias: Xb dead after qkv_gemm
  u16* Wqb = (u16*)(ws + (size_t)33554432);    // 2 MB each
  u16* Wkb = (u16*)(ws + (size_t)35651584);
  u16* Wvb = (u16*)(ws + (size_t)37748736);
  u16* Wob = (u16*)(ws + (size_t)39845888);    // ends at 40 MB

  dim3 blk(256);
  conv_bf16<<<4096, blk, 0, stream>>>(X, Wq, Wk, Wv, Wo, Xb, Wqb, Wkb, Wvb, Wob);
  qkv_gemm<<<dim3(8, 32, 3), blk, 0, stream>>>(Xb, Wqb, Wkb, Wvb, bq, bk, bv, Qb, Kb, Vt);
  attn_v2<<<dim3(32, 32), blk, 0, stream>>>(Qb, Kb, Vt, vlen, Ao);
  out_gemm<<<dim3(8, 32), blk, 0, stream>>>(Ao, Wob, bo, (float*)d_out);
}

// Round 3
// 146.170 us; speedup vs baseline: 2.5466x; 1.1530x over previous
//
#include <hip/hip_runtime.h>

#define SQ 2048
#define DM 1024
#define NH 16
#define HD 64

typedef __bf16 bf16x8 __attribute__((ext_vector_type(8)));
typedef float f32x4 __attribute__((ext_vector_type(4)));
typedef unsigned short u16;
typedef unsigned int u32;

// fp32 -> bf16 round-to-nearest-even (bulk convert pass)
__device__ __forceinline__ u16 f2b(float f) {
  union { float f; u32 u; } c; c.f = f;
  return (u16)((c.u + 0x7FFFu + ((c.u >> 16) & 1u)) >> 16);
}

// async global->LDS, 16B per lane; lds dest = wave-uniform base + lane*16
__device__ __forceinline__ void gll16(const void* g, void* l) {
  __builtin_amdgcn_global_load_lds(
      (const __attribute__((address_space(1))) void*)g,
      (__attribute__((address_space(3))) void*)l, 16, 0, 0);
}

// ---------------------------------------------------------------------------
// fp32 -> bf16 convert pass: X (4M elems) + Wq/Wk/Wv/Wo (1M each)
// ---------------------------------------------------------------------------
__global__ void __launch_bounds__(256) conv_bf16(
    const float* __restrict__ X,
    const float* __restrict__ Wq, const float* __restrict__ Wk,
    const float* __restrict__ Wv, const float* __restrict__ Wo,
    u16* __restrict__ Xb, u16* __restrict__ Wqb, u16* __restrict__ Wkb,
    u16* __restrict__ Wvb, u16* __restrict__ Wob) {
  const size_t e = ((size_t)blockIdx.x * 256 + threadIdx.x) * 8;
  const float* src; u16* dst; size_t rel;
  if (e < 4194304u)      { src = X;  dst = Xb;  rel = e; }
  else if (e < 5242880u) { src = Wq; dst = Wqb; rel = e - 4194304u; }
  else if (e < 6291456u) { src = Wk; dst = Wkb; rel = e - 5242880u; }
  else if (e < 7340032u) { src = Wv; dst = Wvb; rel = e - 6291456u; }
  else                   { src = Wo; dst = Wob; rel = e - 7340032u; }
  float4 a = *(const float4*)(src + rel);
  float4 b = *(const float4*)(src + rel + 4);
  union { u16 h[8]; uint4 v; } o;
  o.h[0] = f2b(a.x); o.h[1] = f2b(a.y); o.h[2] = f2b(a.z); o.h[3] = f2b(a.w);
  o.h[4] = f2b(b.x); o.h[5] = f2b(b.y); o.h[6] = f2b(b.z); o.h[7] = f2b(b.w);
  *(uint4*)(dst + rel) = o.v;
}

// ---------------------------------------------------------------------------
// m97-style 128x128 NT GEMM core, bf16 inputs, BK=32, global_load_lds staging,
// double-buffered LDS ([2][128][32] linear per operand), 2-phase schedule.
// ---------------------------------------------------------------------------
__device__ __forceinline__ void stage128(const u16* __restrict__ A, const u16* __restrict__ B,
                                         u16* sA, u16* sB, int m0, int n0, int kt,
                                         int w, int l) {
#pragma unroll
  for (int c = 0; c < 2; ++c) {
    const int g = w * 2 + c;       // chunk-group 0..7 (1 KB each)
    const int s = g * 64 + l;      // 16B slot 0..511
    const int r = s >> 2, cc = s & 3;
    gll16(A + (size_t)(m0 + r) * DM + kt * 32 + cc * 8, sA + g * 512);
    gll16(B + (size_t)(n0 + r) * DM + kt * 32 + cc * 8, sB + g * 512);
  }
}

__device__ __forceinline__ void gemm_core2(const u16* __restrict__ A, const u16* __restrict__ B,
                                           u16* sA, u16* sB,   // each [2][4096] u16
                                           int m0, int n0, f32x4 acc[4][4]) {
  const int t = threadIdx.x, l = t & 63, w = t >> 6;
  const int wr = w >> 1, wc = w & 1, lg = l >> 4, li = l & 15;

  stage128(A, B, sA, sB, m0, n0, 0, w, l);
  __syncthreads();  // drains vmcnt(0) before barrier
  int cur = 0;
  for (int kt = 0; kt < DM / 32; ++kt) {
    if (kt + 1 < DM / 32)
      stage128(A, B, sA + (cur ^ 1) * 4096, sB + (cur ^ 1) * 4096, m0, n0, kt + 1, w, l);
    bf16x8 aF[4], bF[4];
#pragma unroll
    for (int mi = 0; mi < 4; ++mi)
      aF[mi] = *(const bf16x8*)(sA + cur * 4096 + (wr * 64 + mi * 16 + li) * 32 + lg * 8);
#pragma unroll
    for (int ni = 0; ni < 4; ++ni)
      bF[ni] = *(const bf16x8*)(sB + cur * 4096 + (wc * 64 + ni * 16 + li) * 32 + lg * 8);
#pragma unroll
    for (int mi = 0; mi < 4; ++mi)
#pragma unroll
      for (int ni = 0; ni < 4; ++ni)
        acc[mi][ni] = __builtin_amdgcn_mfma_f32_16x16x32_bf16(aF[mi], bF[ni], acc[mi][ni], 0, 0, 0);
    __syncthreads();
    cur ^= 1;
  }
}

// ---------------------------------------------------------------------------
// QKV projection (bf16 in): z = 0:Q (scaled log2e/8), 1:K, 2:V^T ([bh][dd][s])
// ---------------------------------------------------------------------------
__global__ void __launch_bounds__(256) qkv_gemm(
    const u16* __restrict__ Xb,
    const u16* __restrict__ Wqb, const u16* __restrict__ Wkb, const u16* __restrict__ Wvb,
    const float* __restrict__ bq, const float* __restrict__ bk, const float* __restrict__ bv,
    u16* __restrict__ Qb, u16* __restrict__ Kb, u16* __restrict__ Vt) {
  __shared__ u16 sA[8192];
  __shared__ u16 sB[8192];
  const int mode = blockIdx.z;
  const u16* W = (mode == 0) ? Wqb : (mode == 1) ? Wkb : Wvb;
  const float* bias = (mode == 0) ? bq : (mode == 1) ? bk : bv;
  const int m0 = blockIdx.y * 128, n0 = blockIdx.x * 128;

  f32x4 acc[4][4];
  f32x4 z4 = {0.f, 0.f, 0.f, 0.f};
#pragma unroll
  for (int i = 0; i < 4; ++i)
#pragma unroll
    for (int j = 0; j < 4; ++j) acc[i][j] = z4;

  gemm_core2(Xb, W, sA, sB, m0, n0, acc);

  const int t = threadIdx.x;
  const int l = t & 63, w = t >> 6;
  const int wr = w >> 1, wc = w & 1, lg = l >> 4, li = l & 15;
#pragma unroll
  for (int mi = 0; mi < 4; ++mi) {
    const int m = m0 + wr * 64 + mi * 16 + lg * 4;
    const int b = m >> 11;           // batch
    const int s = m & 2047;          // seq pos
#pragma unroll
    for (int ni = 0; ni < 4; ++ni) {
      const int n = n0 + wc * 64 + ni * 16 + li;
      const int h = n >> 6, dd = n & 63;
      const float bia = bias[n];
      const size_t bh = (size_t)(b * NH + h);
#pragma unroll
      for (int r = 0; r < 4; ++r) {
        const float val = acc[mi][ni][r] + bia;
        const int ss = s + r;
        // Q prescale: (1/sqrt(HD)) * log2(e) so attn works in exp2 domain
        if (mode == 0)      Qb[(bh * SQ + ss) * HD + dd] = f2b(val * 0.180336880f);
        else if (mode == 1) Kb[(bh * SQ + ss) * HD + dd] = f2b(val);
        else                Vt[(bh * HD + dd) * SQ + ss] = f2b(val);
      }
    }
  }
}

// ---------------------------------------------------------------------------
// Final projection: out = Ao * Wo^T + bo (bf16 in, fp32 out)
// ---------------------------------------------------------------------------
__global__ void __launch_bounds__(256) out_gemm(
    const u16* __restrict__ Ag, const u16* __restrict__ Wob,
    const float* __restrict__ bo, float* __restrict__ out) {
  __shared__ u16 sA[8192];
  __shared__ u16 sB[8192];
  const int m0 = blockIdx.y * 128, n0 = blockIdx.x * 128;

  f32x4 acc[4][4];
  f32x4 z4 = {0.f, 0.f, 0.f, 0.f};
#pragma unroll
  for (int i = 0; i < 4; ++i)
#pragma unroll
    for (int j = 0; j < 4; ++j) acc[i][j] = z4;

  gemm_core2(Ag, Wob, sA, sB, m0, n0, acc);

  const int t = threadIdx.x;
  const int l = t & 63, w = t >> 6;
  const int wr = w >> 1, wc = w & 1, lg = l >> 4, li = l & 15;
#pragma unroll
  for (int mi = 0; mi < 4; ++mi) {
    const int m = m0 + wr * 64 + mi * 16 + lg * 4;
#pragma unroll
    for (int ni = 0; ni < 4; ++ni) {
      const int n = n0 + wc * 64 + ni * 16 + li;
      const float bia = bo[n];
#pragma unroll
      for (int r = 0; r < 4; ++r)
        out[(size_t)(m + r) * DM + n] = acc[mi][ni][r] + bia;
    }
  }
}

// ---------------------------------------------------------------------------
// Flash attention v3:
//  - swapped QK^T (mfma(K,Q)) -> query-per-lane softmax
//  - sigma-permuted K rows in LDS so each lane's scores ARE its PV B-frag
//    keys: P -> PV with zero cross-lane ops (key permutation is free since
//    MFMA sums over K and masking is query-only)
//  - log2-domain softmax (Q prescaled by log2e/8), exp2 direct
//  - masked queries via qf=0 (uniform softmax == reference row-mask semantics)
//  - defer-max rescale threshold (T13)
// ---------------------------------------------------------------------------
__global__ void __launch_bounds__(256) attn_v3(
    const u16* __restrict__ Qb, const u16* __restrict__ Kb, const u16* __restrict__ Vt,
    const int* __restrict__ vlen, u16* __restrict__ Ao) {
  __shared__ u16 sK[2][4096];   // [64 keys(sigma-permuted)][64 dk], chunk-XOR swizzled
  __shared__ u16 sV[2][4096];   // [64 d][64 keys], chunk-XOR swizzled
  const int bh = blockIdx.y, qt = blockIdx.x;
  const int t = threadIdx.x, w = t >> 6, l = t & 63, lg = l >> 4, li = l & 15;
  const int vl = vlen[bh];
  const u16* Qh = Qb + (size_t)bh * SQ * HD;
  const u16* Kh = Kb + (size_t)bh * SQ * HD;
  const u16* Vh = Vt + (size_t)bh * HD * SQ;
  const int q0 = qt * 64 + w * 16;        // this wave's 16 queries
  const bool mq = (q0 + li) >= vl;        // per-lane query mask

  // Q fragment (B operand): lane holds Q[q0+li][kk*32 + lg*8 .. +7]
  // masked query -> qf = 0 -> all scores equal -> uniform softmax (= reference)
  bf16x8 qf[2];
#pragma unroll
  for (int kk = 0; kk < 2; ++kk) {
    qf[kk] = *(const bf16x8*)(Qh + (size_t)(q0 + li) * HD + kk * 32 + lg * 8);
    if (mq) {
      union { u32 u[4]; bf16x8 v; } z; z.u[0] = z.u[1] = z.u[2] = z.u[3] = 0;
      qf[kk] = z.v;
    }
  }

  // loop-invariant staging geometry (per-lane global offsets, linear LDS dest)
  int gq[2]; size_t kOff[2], vOff[2];
#pragma unroll
  for (int c = 0; c < 2; ++c) {
    gq[c] = w * 2 + c;                 // 1KB chunk-group 0..7
    const int s = gq[c] * 64 + l;      // 16B slot 0..511
    const int r = s >> 3, cs = s & 7;
    const int csrc = cs ^ (r & 7);     // inverse chunk swizzle on source
    // sigma: LDS row r holds global key sig(r) (bit permute: b4->b2,b3->b4,b2->b3)
    const int sig = (r & 32) | (((r >> 2) & 3) << 3) | (((r >> 4) & 1) << 2) | (r & 3);
    kOff[c] = (size_t)sig * HD + csrc * 8;
    vOff[c] = (size_t)r * SQ + csrc * 8;
  }

  auto stageKV = [&](int buf, int kt) {
#pragma unroll
    for (int c = 0; c < 2; ++c) {
      gll16(Kh + (size_t)(kt * 64) * HD + kOff[c], &sK[buf][gq[c] * 512]);
      gll16(Vh + (size_t)(kt * 64) + vOff[c], &sV[buf][gq[c] * 512]);
    }
  };

  float m_r = -1e30f, l_r = 0.f;
  f32x4 z4 = {0.f, 0.f, 0.f, 0.f};
  f32x4 acc[4];                        // O^T: acc[ni][r] = O^T[ni*16+lg*4+r][q0+li]
#pragma unroll
  for (int ni = 0; ni < 4; ++ni) acc[ni] = z4;

  stageKV(0, 0);
  __syncthreads();
  int cur = 0;
  for (int kt = 0; kt < SQ / 64; ++kt) {
    if (kt + 1 < SQ / 64) stageKV(cur ^ 1, kt + 1);

    // S^T = K Q^T (log2 domain): sc[ni][r] = score of key sig(ni*16+lg*4+r), query q0+li
    f32x4 sc[4];
#pragma unroll
    for (int ni = 0; ni < 4; ++ni) {
      f32x4 s = z4;
#pragma unroll
      for (int kk = 0; kk < 2; ++kk) {
        const int row = ni * 16 + li;
        bf16x8 kf = *(const bf16x8*)(&sK[cur][row * 64 + (((kk * 4 + lg) ^ (row & 7)) * 8)]);
        s = __builtin_amdgcn_mfma_f32_16x16x32_bf16(kf, qf[kk], s, 0, 0, 0);
      }
      sc[ni] = s;
    }

    // online softmax, query-per-lane; reduce across the 4 lanes sharing query li
    float pm = -3.0e38f;
#pragma unroll
    for (int ni = 0; ni < 4; ++ni)
#pragma unroll
      for (int r = 0; r < 4; ++r) pm = fmaxf(pm, sc[ni][r]);
    pm = fmaxf(pm, __shfl_xor(pm, 16));
    pm = fmaxf(pm, __shfl_xor(pm, 32));

    const bool defer = __all(pm - m_r <= 10.0f) != 0;   // T13: P bounded by 2^10
    const float mn = defer ? m_r : fmaxf(m_r, pm);

    float p[4][4];
    float ls = 0.f;
#pragma unroll
    for (int ni = 0; ni < 4; ++ni)
#pragma unroll
      for (int r = 0; r < 4; ++r) {
        p[ni][r] = __builtin_amdgcn_exp2f(sc[ni][r] - mn);
        ls += p[ni][r];
      }
    ls += __shfl_xor(ls, 16);
    ls += __shfl_xor(ls, 32);

    if (defer) {
      l_r += ls;
    } else {
      const float al = __builtin_amdgcn_exp2f(m_r - mn);
#pragma unroll
      for (int ni = 0; ni < 4; ++ni) acc[ni] *= al;
      l_r = l_r * al + ls;
      m_r = mn;
    }

    // zero-shuffle P -> PV B-frags (keys were sigma-permuted at K staging):
    // pb[kk] elem e = p[kk*2 + (e>>2)][e&3]
    union { __bf16 h[8]; bf16x8 v; } pbA, pbB;
#pragma unroll
    for (int j = 0; j < 4; ++j) {
      pbA.h[j]     = (__bf16)p[0][j];
      pbA.h[4 + j] = (__bf16)p[1][j];
      pbB.h[j]     = (__bf16)p[2][j];
      pbB.h[4 + j] = (__bf16)p[3][j];
    }

    // O^T += V^T P^T
#pragma unroll
    for (int ni = 0; ni < 4; ++ni) {
#pragma unroll
      for (int kk = 0; kk < 2; ++kk) {
        const int row = ni * 16 + li;
        bf16x8 vf = *(const bf16x8*)(&sV[cur][row * 64 + (((kk * 4 + lg) ^ (row & 7)) * 8)]);
        acc[ni] = __builtin_amdgcn_mfma_f32_16x16x32_bf16(vf, kk ? pbB.v : pbA.v, acc[ni], 0, 0, 0);
      }
    }

    __syncthreads();
    cur ^= 1;
  }

  // epilogue: normalize, write bf16 Ao[b][s][h*64+d] (8B stores)
  const int b = bh >> 4, h = bh & 15;
  const float inv = 1.0f / l_r;
#pragma unroll
  for (int ni = 0; ni < 4; ++ni) {
    union { __bf16 h2[4]; uint2 u; } ov;
#pragma unroll
    for (int r = 0; r < 4; ++r) ov.h2[r] = (__bf16)(acc[ni][r] * inv);
    const size_t off = ((size_t)(b * SQ + q0 + li)) * DM + h * HD + ni * 16 + lg * 4;
    *(uint2*)(Ao + off) = ov.u;
  }
}

extern "C" void kernel_launch(void* const* d_in, const int* in_sizes, int n_in,
                              void* d_out, int out_size, void* d_ws, size_t ws_size,
                              hipStream_t stream) {
  const float* X  = (const float*)d_in[0];
  const float* Wq = (const float*)d_in[1];
  const float* bq = (const float*)d_in[2];
  const float* Wk = (const float*)d_in[3];
  const float* bk = (const float*)d_in[4];
  const float* Wv = (const float*)d_in[5];
  const float* bv = (const float*)d_in[6];
  const float* Wo = (const float*)d_in[7];
  const float* bo = (const float*)d_in[8];
  const int* vlen = (const int*)d_in[9];

  char* ws = (char*)d_ws;
  u16* Qb  = (u16*)(ws);                       // 8 MB [32][2048][64]
  u16* Kb  = (u16*)(ws + (size_t)8388608);     // 8 MB
  u16* Vt  = (u16*)(ws + (size_t)16777216);    // 8 MB [32][64][2048]
  u16* Xb  = (u16*)(ws + (size_t)25165824);    // 8 MB [4096][1024] bf16
  u16* Ao  = Xb;                               // alias: Xb dead after qkv_gemm
  u16* Wqb = (u16*)(ws + (size_t)33554432);    // 2 MB each
  u16* Wkb = (u16*)(ws + (size_t)35651584);
  u16* Wvb = (u16*)(ws + (size_t)37748736);
  u16* Wob = (u16*)(ws + (size_t)39845888);    // ends at 40 MB

  dim3 blk(256);
  conv_bf16<<<4096, blk, 0, stream>>>(X, Wq, Wk, Wv, Wo, Xb, Wqb, Wkb, Wvb, Wob);
  qkv_gemm<<<dim3(8, 32, 3), blk, 0, stream>>>(Xb, Wqb, Wkb, Wvb, bq, bk, bv, Qb, Kb, Vt);
  attn_v3<<<dim3(32, 32), blk, 0, stream>>>(Qb, Kb, Vt, vlen, Ao);
  out_gemm<<<dim3(8, 32), blk, 0, stream>>>(Ao, Wob, bo, (float*)d_out);
}

// Round 4
// 140.996 us; speedup vs baseline: 2.6400x; 1.0367x over previous
//
#include <hip/hip_runtime.h>

#define SQ 2048
#define DM 1024
#define NH 16
#define HD 64

typedef __bf16 bf16x8 __attribute__((ext_vector_type(8)));
typedef float f32x4 __attribute__((ext_vector_type(4)));
typedef unsigned short u16;
typedef unsigned int u32;

// fp32 -> bf16 round-to-nearest-even (bulk convert pass)
__device__ __forceinline__ u16 f2b(float f) {
  union { float f; u32 u; } c; c.f = f;
  return (u16)((c.u + 0x7FFFu + ((c.u >> 16) & 1u)) >> 16);
}

// async global->LDS, 16B per lane; lds dest = wave-uniform base + lane*16
__device__ __forceinline__ void gll16(const void* g, void* l) {
  __builtin_amdgcn_global_load_lds(
      (const __attribute__((address_space(1))) void*)g,
      (__attribute__((address_space(3))) void*)l, 16, 0, 0);
}

// ---------------------------------------------------------------------------
// fp32 -> bf16 convert pass: X (4M elems) + Wq/Wk/Wv/Wo (1M each)
// ---------------------------------------------------------------------------
__global__ void __launch_bounds__(256) conv_bf16(
    const float* __restrict__ X,
    const float* __restrict__ Wq, const float* __restrict__ Wk,
    const float* __restrict__ Wv, const float* __restrict__ Wo,
    u16* __restrict__ Xb, u16* __restrict__ Wqb, u16* __restrict__ Wkb,
    u16* __restrict__ Wvb, u16* __restrict__ Wob) {
  const size_t e = ((size_t)blockIdx.x * 256 + threadIdx.x) * 8;
  const float* src; u16* dst; size_t rel;
  if (e < 4194304u)      { src = X;  dst = Xb;  rel = e; }
  else if (e < 5242880u) { src = Wq; dst = Wqb; rel = e - 4194304u; }
  else if (e < 6291456u) { src = Wk; dst = Wkb; rel = e - 5242880u; }
  else if (e < 7340032u) { src = Wv; dst = Wvb; rel = e - 6291456u; }
  else                   { src = Wo; dst = Wob; rel = e - 7340032u; }
  float4 a = *(const float4*)(src + rel);
  float4 b = *(const float4*)(src + rel + 4);
  union { u16 h[8]; uint4 v; } o;
  o.h[0] = f2b(a.x); o.h[1] = f2b(a.y); o.h[2] = f2b(a.z); o.h[3] = f2b(a.w);
  o.h[4] = f2b(b.x); o.h[5] = f2b(b.y); o.h[6] = f2b(b.z); o.h[7] = f2b(b.w);
  *(uint4*)(dst + rel) = o.v;
}

// ---------------------------------------------------------------------------
// m97-style 128x128 NT GEMM core, bf16 inputs, BK=32, global_load_lds staging,
// double-buffered LDS ([2][128][32] linear per operand), 2-phase schedule.
// ---------------------------------------------------------------------------
__device__ __forceinline__ void stage128(const u16* __restrict__ A, const u16* __restrict__ B,
                                         u16* sA, u16* sB, int m0, int n0, int kt,
                                         int w, int l) {
#pragma unroll
  for (int c = 0; c < 2; ++c) {
    const int g = w * 2 + c;       // chunk-group 0..7 (1 KB each)
    const int s = g * 64 + l;      // 16B slot 0..511
    const int r = s >> 2, cc = s & 3;
    gll16(A + (size_t)(m0 + r) * DM + kt * 32 + cc * 8, sA + g * 512);
    gll16(B + (size_t)(n0 + r) * DM + kt * 32 + cc * 8, sB + g * 512);
  }
}

__device__ __forceinline__ void gemm_core2(const u16* __restrict__ A, const u16* __restrict__ B,
                                           u16* sA, u16* sB,   // each [2][4096] u16
                                           int m0, int n0, f32x4 acc[4][4]) {
  const int t = threadIdx.x, l = t & 63, w = t >> 6;
  const int wr = w >> 1, wc = w & 1, lg = l >> 4, li = l & 15;

  stage128(A, B, sA, sB, m0, n0, 0, w, l);
  __syncthreads();  // drains vmcnt(0) before barrier
  int cur = 0;
  for (int kt = 0; kt < DM / 32; ++kt) {
    if (kt + 1 < DM / 32)
      stage128(A, B, sA + (cur ^ 1) * 4096, sB + (cur ^ 1) * 4096, m0, n0, kt + 1, w, l);
    bf16x8 aF[4], bF[4];
#pragma unroll
    for (int mi = 0; mi < 4; ++mi)
      aF[mi] = *(const bf16x8*)(sA + cur * 4096 + (wr * 64 + mi * 16 + li) * 32 + lg * 8);
#pragma unroll
    for (int ni = 0; ni < 4; ++ni)
      bF[ni] = *(const bf16x8*)(sB + cur * 4096 + (wc * 64 + ni * 16 + li) * 32 + lg * 8);
#pragma unroll
    for (int mi = 0; mi < 4; ++mi)
#pragma unroll
      for (int ni = 0; ni < 4; ++ni)
        acc[mi][ni] = __builtin_amdgcn_mfma_f32_16x16x32_bf16(aF[mi], bF[ni], acc[mi][ni], 0, 0, 0);
    __syncthreads();
    cur ^= 1;
  }
}

// ---------------------------------------------------------------------------
// QKV projection (bf16 in): z = 0:Q (scaled log2e/8), 1:K, 2:V^T ([bh][dd][s])
// ---------------------------------------------------------------------------
__global__ void __launch_bounds__(256) qkv_gemm(
    const u16* __restrict__ Xb,
    const u16* __restrict__ Wqb, const u16* __restrict__ Wkb, const u16* __restrict__ Wvb,
    const float* __restrict__ bq, const float* __restrict__ bk, const float* __restrict__ bv,
    u16* __restrict__ Qb, u16* __restrict__ Kb, u16* __restrict__ Vt) {
  __shared__ u16 sA[8192];
  __shared__ u16 sB[8192];
  const int mode = blockIdx.z;
  const u16* W = (mode == 0) ? Wqb : (mode == 1) ? Wkb : Wvb;
  const float* bias = (mode == 0) ? bq : (mode == 1) ? bk : bv;
  const int m0 = blockIdx.y * 128, n0 = blockIdx.x * 128;

  f32x4 acc[4][4];
  f32x4 z4 = {0.f, 0.f, 0.f, 0.f};
#pragma unroll
  for (int i = 0; i < 4; ++i)
#pragma unroll
    for (int j = 0; j < 4; ++j) acc[i][j] = z4;

  gemm_core2(Xb, W, sA, sB, m0, n0, acc);

  const int t = threadIdx.x;
  const int l = t & 63, w = t >> 6;
  const int wr = w >> 1, wc = w & 1, lg = l >> 4, li = l & 15;
#pragma unroll
  for (int mi = 0; mi < 4; ++mi) {
    const int m = m0 + wr * 64 + mi * 16 + lg * 4;
    const int b = m >> 11;           // batch
    const int s = m & 2047;          // seq pos
#pragma unroll
    for (int ni = 0; ni < 4; ++ni) {
      const int n = n0 + wc * 64 + ni * 16 + li;
      const int h = n >> 6, dd = n & 63;
      const float bia = bias[n];
      const size_t bh = (size_t)(b * NH + h);
#pragma unroll
      for (int r = 0; r < 4; ++r) {
        const float val = acc[mi][ni][r] + bia;
        const int ss = s + r;
        // Q prescale: (1/sqrt(HD)) * log2(e) so attn works in exp2 domain
        if (mode == 0)      Qb[(bh * SQ + ss) * HD + dd] = f2b(val * 0.180336880f);
        else if (mode == 1) Kb[(bh * SQ + ss) * HD + dd] = f2b(val);
        else                Vt[(bh * HD + dd) * SQ + ss] = f2b(val);
      }
    }
  }
}

// ---------------------------------------------------------------------------
// Final projection: out = Ao * Wo^T + bo (bf16 in, fp32 out)
// ---------------------------------------------------------------------------
__global__ void __launch_bounds__(256) out_gemm(
    const u16* __restrict__ Ag, const u16* __restrict__ Wob,
    const float* __restrict__ bo, float* __restrict__ out) {
  __shared__ u16 sA[8192];
  __shared__ u16 sB[8192];
  const int m0 = blockIdx.y * 128, n0 = blockIdx.x * 128;

  f32x4 acc[4][4];
  f32x4 z4 = {0.f, 0.f, 0.f, 0.f};
#pragma unroll
  for (int i = 0; i < 4; ++i)
#pragma unroll
    for (int j = 0; j < 4; ++j) acc[i][j] = z4;

  gemm_core2(Ag, Wob, sA, sB, m0, n0, acc);

  const int t = threadIdx.x;
  const int l = t & 63, w = t >> 6;
  const int wr = w >> 1, wc = w & 1, lg = l >> 4, li = l & 15;
#pragma unroll
  for (int mi = 0; mi < 4; ++mi) {
    const int m = m0 + wr * 64 + mi * 16 + lg * 4;
#pragma unroll
    for (int ni = 0; ni < 4; ++ni) {
      const int n = n0 + wc * 64 + ni * 16 + li;
      const float bia = bo[n];
#pragma unroll
      for (int r = 0; r < 4; ++r)
        out[(size_t)(m + r) * DM + n] = acc[mi][ni][r] + bia;
    }
  }
}

// ---------------------------------------------------------------------------
// Per-group online softmax + P packing.
// Hot path: p = exp2(sc - m_r) anchored at previous max (no cross-lane dep);
// max-tree + __all defer-check run in parallel; cold rescale is wave-uniform.
// l_r stays a per-lane partial (reduced once in epilogue).
// ---------------------------------------------------------------------------
__device__ __forceinline__ void softmax_group(
    f32x4 sc[4], float& m_r, float& l_r, f32x4 acc[4],
    bf16x8& pb0, bf16x8& pb1) {
  // per-lane max tree (depth 4; fmax pairs fuse to v_max3 where possible)
  float ma = fmaxf(fmaxf(sc[0][0], sc[0][1]), fmaxf(sc[0][2], sc[0][3]));
  float mb = fmaxf(fmaxf(sc[1][0], sc[1][1]), fmaxf(sc[1][2], sc[1][3]));
  float mc = fmaxf(fmaxf(sc[2][0], sc[2][1]), fmaxf(sc[2][2], sc[2][3]));
  float md = fmaxf(fmaxf(sc[3][0], sc[3][1]), fmaxf(sc[3][2], sc[3][3]));
  const float pm = fmaxf(fmaxf(ma, mb), fmaxf(mc, md));

  // anchored exp2 — starts immediately, independent of the max tree
  float p[4][4];
#pragma unroll
  for (int ni = 0; ni < 4; ++ni)
#pragma unroll
    for (int r = 0; r < 4; ++r)
      p[ni][r] = __builtin_amdgcn_exp2f(sc[ni][r] - m_r);

  if (__builtin_expect(!__all(pm - m_r <= 10.0f), 0)) {
    // cold: true rescale (wave-uniform branch)
    float pf = fmaxf(pm, __shfl_xor(pm, 16));
    pf = fmaxf(pf, __shfl_xor(pf, 32));
    const float mn = fmaxf(m_r, pf);
    const float al = __builtin_amdgcn_exp2f(m_r - mn);
#pragma unroll
    for (int ni = 0; ni < 4; ++ni) {
#pragma unroll
      for (int r = 0; r < 4; ++r) p[ni][r] *= al;
      acc[ni] *= al;
    }
    l_r *= al;
    m_r = mn;
  }

  // per-lane partial sum (tree, depth 4)
  float s0 = (p[0][0] + p[0][1]) + (p[0][2] + p[0][3]);
  float s1 = (p[1][0] + p[1][1]) + (p[1][2] + p[1][3]);
  float s2 = (p[2][0] + p[2][1]) + (p[2][2] + p[2][3]);
  float s3 = (p[3][0] + p[3][1]) + (p[3][2] + p[3][3]);
  l_r += (s0 + s1) + (s2 + s3);

  // pack P -> PV B-frags (keys sigma-permuted at staging: in-order pack)
  union { __bf16 h[8]; bf16x8 v; } A, B;
#pragma unroll
  for (int j = 0; j < 4; ++j) {
    A.h[j]     = (__bf16)p[0][j];
    A.h[4 + j] = (__bf16)p[1][j];
    B.h[j]     = (__bf16)p[2][j];
    B.h[4 + j] = (__bf16)p[3][j];
  }
  pb0 = A.v; pb1 = B.v;
}

// ---------------------------------------------------------------------------
// Flash attention v4: 32 queries/wave (2 groups sharing K/V frags),
// sigma-permuted K (zero-shuffle P->PV), log2-domain anchored softmax,
// per-lane l partials, masked queries via qf=0. Grid 16x32.
// ---------------------------------------------------------------------------
__global__ void __launch_bounds__(256) attn_v4(
    const u16* __restrict__ Qb, const u16* __restrict__ Kb, const u16* __restrict__ Vt,
    const int* __restrict__ vlen, u16* __restrict__ Ao) {
  __shared__ u16 sK[2][4096];   // [64 keys(sigma)][64 dk], chunk-XOR swizzled
  __shared__ u16 sV[2][4096];   // [64 d][64 keys], chunk-XOR swizzled
  const int bh = blockIdx.y, qt = blockIdx.x;
  const int t = threadIdx.x, w = t >> 6, l = t & 63, lg = l >> 4, li = l & 15;
  const int vl = vlen[bh];
  const u16* Qh = Qb + (size_t)bh * SQ * HD;
  const u16* Kh = Kb + (size_t)bh * SQ * HD;
  const u16* Vh = Vt + (size_t)bh * HD * SQ;
  const int q0w = qt * 128 + w * 32;      // wave's 32 queries: q0w + g*16 + li

  // Q fragments, masked queries zeroed (uniform softmax == reference row-mask)
  bf16x8 qf[2][2];
#pragma unroll
  for (int g = 0; g < 2; ++g) {
    const bool mq = (q0w + g * 16 + li) >= vl;
#pragma unroll
    for (int kk = 0; kk < 2; ++kk) {
      qf[g][kk] = *(const bf16x8*)(Qh + (size_t)(q0w + g * 16 + li) * HD + kk * 32 + lg * 8);
      if (mq) {
        union { u32 u[4]; bf16x8 v; } z; z.u[0] = z.u[1] = z.u[2] = z.u[3] = 0;
        qf[g][kk] = z.v;
      }
    }
  }

  // loop-invariant staging geometry
  int gq[2]; size_t kOff[2], vOff[2];
#pragma unroll
  for (int c = 0; c < 2; ++c) {
    gq[c] = w * 2 + c;
    const int s = gq[c] * 64 + l;
    const int r = s >> 3, cs = s & 7;
    const int csrc = cs ^ (r & 7);
    const int sig = (r & 32) | (((r >> 2) & 3) << 3) | (((r >> 4) & 1) << 2) | (r & 3);
    kOff[c] = (size_t)sig * HD + csrc * 8;
    vOff[c] = (size_t)r * SQ + csrc * 8;
  }
  auto stageKV = [&](int buf, int kt) {
#pragma unroll
    for (int c = 0; c < 2; ++c) {
      gll16(Kh + (size_t)(kt * 64) * HD + kOff[c], &sK[buf][gq[c] * 512]);
      gll16(Vh + (size_t)(kt * 64) + vOff[c], &sV[buf][gq[c] * 512]);
    }
  };

  float m_r[2] = {0.f, 0.f};      // safe anchor: scores ~N(0,0.5), masked rows = 0
  float l_r[2] = {0.f, 0.f};
  f32x4 z4 = {0.f, 0.f, 0.f, 0.f};
  f32x4 acc0[4], acc1[4];
#pragma unroll
  for (int ni = 0; ni < 4; ++ni) { acc0[ni] = z4; acc1[ni] = z4; }

  stageKV(0, 0);
  __syncthreads();
  int cur = 0;
  for (int kt = 0; kt < SQ / 64; ++kt) {
    if (kt + 1 < SQ / 64) stageKV(cur ^ 1, kt + 1);

    // S^T = K Q^T for both query groups (K frags shared)
    f32x4 sc0[4], sc1[4];
#pragma unroll
    for (int ni = 0; ni < 4; ++ni) {
      const int row = ni * 16 + li;
      bf16x8 kf0 = *(const bf16x8*)(&sK[cur][row * 64 + ((lg ^ (row & 7)) * 8)]);
      bf16x8 kf1 = *(const bf16x8*)(&sK[cur][row * 64 + (((4 + lg) ^ (row & 7)) * 8)]);
      sc0[ni] = __builtin_amdgcn_mfma_f32_16x16x32_bf16(kf0, qf[0][0], z4, 0, 0, 0);
      sc0[ni] = __builtin_amdgcn_mfma_f32_16x16x32_bf16(kf1, qf[0][1], sc0[ni], 0, 0, 0);
      sc1[ni] = __builtin_amdgcn_mfma_f32_16x16x32_bf16(kf0, qf[1][0], z4, 0, 0, 0);
      sc1[ni] = __builtin_amdgcn_mfma_f32_16x16x32_bf16(kf1, qf[1][1], sc1[ni], 0, 0, 0);
    }

    bf16x8 pb00, pb01, pb10, pb11;
    softmax_group(sc0, m_r[0], l_r[0], acc0, pb00, pb01);
    softmax_group(sc1, m_r[1], l_r[1], acc1, pb10, pb11);

    // O^T += V^T P^T (V frags shared)
#pragma unroll
    for (int ni = 0; ni < 4; ++ni) {
      const int row = ni * 16 + li;
      bf16x8 vf0 = *(const bf16x8*)(&sV[cur][row * 64 + ((lg ^ (row & 7)) * 8)]);
      bf16x8 vf1 = *(const bf16x8*)(&sV[cur][row * 64 + (((4 + lg) ^ (row & 7)) * 8)]);
      acc0[ni] = __builtin_amdgcn_mfma_f32_16x16x32_bf16(vf0, pb00, acc0[ni], 0, 0, 0);
      acc0[ni] = __builtin_amdgcn_mfma_f32_16x16x32_bf16(vf1, pb01, acc0[ni], 0, 0, 0);
      acc1[ni] = __builtin_amdgcn_mfma_f32_16x16x32_bf16(vf0, pb10, acc1[ni], 0, 0, 0);
      acc1[ni] = __builtin_amdgcn_mfma_f32_16x16x32_bf16(vf1, pb11, acc1[ni], 0, 0, 0);
    }

    __syncthreads();
    cur ^= 1;
  }

  // epilogue: reduce l across the 4 lane-groups, normalize, write bf16 Ao
  const int b = bh >> 4, h = bh & 15;
#pragma unroll
  for (int g = 0; g < 2; ++g) {
    float lf = l_r[g];
    lf += __shfl_xor(lf, 16);
    lf += __shfl_xor(lf, 32);
    const float inv = 1.0f / lf;
    f32x4* ac = g ? acc1 : acc0;
    const size_t rowb = ((size_t)(b * SQ + q0w + g * 16 + li)) * DM + h * HD;
#pragma unroll
    for (int ni = 0; ni < 4; ++ni) {
      union { __bf16 h2[4]; uint2 u; } ov;
#pragma unroll
      for (int r = 0; r < 4; ++r) ov.h2[r] = (__bf16)(ac[ni][r] * inv);
      *(uint2*)(Ao + rowb + ni * 16 + lg * 4) = ov.u;
    }
  }
}

extern "C" void kernel_launch(void* const* d_in, const int* in_sizes, int n_in,
                              void* d_out, int out_size, void* d_ws, size_t ws_size,
                              hipStream_t stream) {
  const float* X  = (const float*)d_in[0];
  const float* Wq = (const float*)d_in[1];
  const float* bq = (const float*)d_in[2];
  const float* Wk = (const float*)d_in[3];
  const float* bk = (const float*)d_in[4];
  const float* Wv = (const float*)d_in[5];
  const float* bv = (const float*)d_in[6];
  const float* Wo = (const float*)d_in[7];
  const float* bo = (const float*)d_in[8];
  const int* vlen = (const int*)d_in[9];

  char* ws = (char*)d_ws;
  u16* Qb  = (u16*)(ws);                       // 8 MB [32][2048][64]
  u16* Kb  = (u16*)(ws + (size_t)8388608);     // 8 MB
  u16* Vt  = (u16*)(ws + (size_t)16777216);    // 8 MB [32][64][2048]
  u16* Xb  = (u16*)(ws + (size_t)25165824);    // 8 MB [4096][1024] bf16
  u16* Ao  = Xb;                               // alias: Xb dead after qkv_gemm
  u16* Wqb = (u16*)(ws + (size_t)33554432);    // 2 MB each
  u16* Wkb = (u16*)(ws + (size_t)35651584);
  u16* Wvb = (u16*)(ws + (size_t)37748736);
  u16* Wob = (u16*)(ws + (size_t)39845888);    // ends at 40 MB

  dim3 blk(256);
  conv_bf16<<<4096, blk, 0, stream>>>(X, Wq, Wk, Wv, Wo, Xb, Wqb, Wkb, Wvb, Wob);
  qkv_gemm<<<dim3(8, 32, 3), blk, 0, stream>>>(Xb, Wqb, Wkb, Wvb, bq, bk, bv, Qb, Kb, Vt);
  attn_v4<<<dim3(16, 32), blk, 0, stream>>>(Qb, Kb, Vt, vlen, Ao);
  out_gemm<<<dim3(8, 32), blk, 0, stream>>>(Ao, Wob, bo, (float*)d_out);
}